// Round 7
// baseline (371.323 us; speedup 1.0000x reference)
//
#include <hip/hip_runtime.h>

typedef __bf16 bf16;
typedef __bf16 bf16x4 __attribute__((ext_vector_type(4)));
typedef __bf16 bf16x8 __attribute__((ext_vector_type(8)));
typedef float f32x4 __attribute__((ext_vector_type(4)));

#define MFMA16(a, b, c) __builtin_amdgcn_mfma_f32_16x16x32_bf16(a, b, c, 0, 0, 0)

// Problem constants: B=8, N=4096, M=256, DIM=256, HEADS=8, DIM_HEAD=64, INNER=512
// exp(S*scale) = exp2(S * 0.125 * log2(e))
#define CEXP 0.18033688011112042f

// ---------------------------------------------------------------------------
// Weight pre-transpose + downcast: W[K,N] fp32 -> WT[N,K] bf16 (10 matrices)
// ---------------------------------------------------------------------------
struct WTArgs {
  const float* src[10];
  bf16* dst[10];
  int K[10];
  int N[10];
};

__global__ __launch_bounds__(256) void wtrans_kernel(WTArgs args) {
  const int z = blockIdx.z;
  const int K = args.K[z], N = args.N[z];
  const int k0 = blockIdx.x * 64, n0 = blockIdx.y * 64;
  if (k0 >= K || n0 >= N) return;
  __shared__ float t[64][65];
  const int tx = threadIdx.x & 63, ty = threadIdx.x >> 6;
  const float* __restrict__ src = args.src[z];
  bf16* __restrict__ dst = args.dst[z];
#pragma unroll
  for (int i = 0; i < 16; ++i)
    t[ty + i * 4][tx] = src[(size_t)(k0 + ty + i * 4) * N + n0 + tx];
  __syncthreads();
#pragma unroll
  for (int i = 0; i < 16; ++i)
    dst[(size_t)(n0 + ty + i * 4) * K + k0 + tx] = (bf16)t[tx][ty + i * 4];
}

// ---------------------------------------------------------------------------
// xq[b][n][c] = feat[b][n][c] + pos[b][c][n]  (fp32 in, bf16 out)
// ---------------------------------------------------------------------------
__global__ __launch_bounds__(256) void prep_xq_kernel(
    const float* __restrict__ feat, const float* __restrict__ pos,
    bf16* __restrict__ xq) {
  const int n0 = blockIdx.x * 64;
  const int c0 = blockIdx.y * 64;
  const int b = blockIdx.z;
  __shared__ float t[64][65];
  const int tx = threadIdx.x & 63, ty = threadIdx.x >> 6;
#pragma unroll
  for (int i = 0; i < 16; ++i) {
    int c = ty + i * 4;
    t[c][tx] = pos[((size_t)b * 256 + c0 + c) * 4096 + n0 + tx];
  }
  __syncthreads();
#pragma unroll
  for (int i = 0; i < 16; ++i) {
    int n = ty + i * 4;
    size_t off = ((size_t)b * 4096 + n0 + n) * 256 + c0 + tx;
    xq[off] = (bf16)(feat[off] + t[tx][n]);
  }
}

// ---------------------------------------------------------------------------
// Staging helper: bf16 async DMA global->LDS (16B/lane, linear dest).
// ---------------------------------------------------------------------------
__device__ inline void stage16(const bf16* g, bf16* l) {
  __builtin_amdgcn_global_load_lds(
      (const __attribute__((address_space(1))) void*)g,
      (__attribute__((address_space(3))) void*)l, 16, 0, 0);
}

// Epilogue helpers: vectorized resid load / C store.
__device__ inline f32x4 rload(const float* p) { return *(const f32x4*)p; }
__device__ inline f32x4 rload(const bf16* p) {
  bf16x4 t = *(const bf16x4*)p;
  return (f32x4){(float)t[0], (float)t[1], (float)t[2], (float)t[3]};
}
__device__ inline void cstore(float* p, f32x4 v) { *(f32x4*)p = v; }
__device__ inline void cstore(bf16* p, f32x4 v) {
  bf16x4 o;
  o[0] = (bf16)v[0]; o[1] = (bf16)v[1]; o[2] = (bf16)v[2]; o[3] = (bf16)v[3];
  *(bf16x4*)p = o;
}

// ---------------------------------------------------------------------------
// Generic GEMM, dual-problem batched via blockIdx.z. C[M,N] = A[M,K] @ B[K,N],
// B pre-transposed BT[N,K]. 128x128 tile, 4 waves, BK=32, double-buffered,
// one barrier per K-step (DMA for t+1 flies under MFMA of t).
// fp32-A path uses T14 async-split: issue global loads after barrier, MFMA,
// THEN cvt+ds_write (the vmcnt wait lands after the MFMA block, not before).
// SWAPPED-OPERAND MFMA -> vectorized epilogue. FUSE2: A=A+A2 (fp32 only).
// EPI: 0=none, 1=relu, 2=+resid, 3=+bias+resid.
// ---------------------------------------------------------------------------
struct GArg {
  const void* A[2];
  const void* A2[2];
  const bf16* BT[2];
  void* C[2];
  const void* resid[2];
  const float* bias[2];
  int M[2];
};

template <int EPI, typename TO, typename TR, typename TA, bool FUSE2>
__global__ __launch_bounds__(256) void gemm_kernel(GArg g, int N, int K) {
  const int z = blockIdx.z;
  const int m0 = blockIdx.x * 128;
  if (m0 >= g.M[z]) return;
  constexpr bool F32A = sizeof(TA) == 4;
  const TA* A = (const TA*)g.A[z];
  const TA* A2 = (const TA*)g.A2[z];
  const bf16* BT = g.BT[z];
  TO* C = (TO*)g.C[z];
  const TR* resid = (const TR*)g.resid[z];
  const float* bias = g.bias[z];

  const int n0 = blockIdx.y * 128;
  const int tid = threadIdx.x;
  const int lane = tid & 63;
  const int w = tid >> 6;
  const int wr = (w >> 1) * 64, wc = (w & 1) * 64;
  const int l15 = lane & 15, quad = lane >> 4;

  __shared__ __align__(16) bf16 Al[2][128 * 32];  // 16KB (dbuf)
  __shared__ __align__(16) bf16 Bl[2][128 * 32];  // 16KB

  f32x4 acc[4][4];
#pragma unroll
  for (int i = 0; i < 4; ++i)
#pragma unroll
    for (int j = 0; j < 4; ++j) acc[i][j] = (f32x4){0.f, 0.f, 0.f, 0.f};

  const int sw = (((l15 >> 1) & 3) ^ quad) * 8;  // read-side swizzled granule

  f32x4 ar[2][2], ar2[2][2];  // fp32-A staging regs (A, optional A2)

  auto stageB = [&](int buf, int k0) {
#pragma unroll
    for (int c = 0; c < 2; ++c) {
      int idx = tid + c * 256;
      int row = idx >> 2;
      int gs = ((idx & 3) ^ ((row >> 1) & 3)) * 8;
      stage16(BT + (size_t)(n0 + row) * K + k0 + gs, Bl[buf] + idx * 8);
    }
  };
  auto stageA_dma = [&](int buf, int k0) {
    if constexpr (!F32A) {
#pragma unroll
      for (int c = 0; c < 2; ++c) {
        int idx = tid + c * 256;
        int row = idx >> 2;
        int gs = ((idx & 3) ^ ((row >> 1) & 3)) * 8;
        stage16((const bf16*)A + (size_t)(m0 + row) * K + k0 + gs,
                Al[buf] + idx * 8);
      }
    }
  };
  auto loadA = [&](int k0) {
    if constexpr (F32A) {
      const float* Af = (const float*)(const void*)A;
      const float* A2f = (const float*)(const void*)A2;
#pragma unroll
      for (int c = 0; c < 2; ++c) {
        int idx = tid + c * 256;
        int row = idx >> 2;
        int gs = ((idx & 3) ^ ((row >> 1) & 3)) * 8;
        const float* p = Af + (size_t)(m0 + row) * K + k0 + gs;
        ar[c][0] = *(const f32x4*)p;
        ar[c][1] = *((const f32x4*)p + 1);
        if constexpr (FUSE2) {
          const float* p2 = A2f + (size_t)(m0 + row) * K + k0 + gs;
          ar2[c][0] = *(const f32x4*)p2;
          ar2[c][1] = *((const f32x4*)p2 + 1);
        }
      }
    }
  };
  auto writeA = [&](int buf) {
    if constexpr (F32A) {
#pragma unroll
      for (int c = 0; c < 2; ++c) {
        int idx = tid + c * 256;
        f32x4 u = ar[c][0], v = ar[c][1];
        if constexpr (FUSE2) {
          u += ar2[c][0];
          v += ar2[c][1];
        }
        bf16x8 o;
#pragma unroll
        for (int e = 0; e < 4; ++e) {
          o[e] = (bf16)u[e];
          o[4 + e] = (bf16)v[e];
        }
        *(bf16x8*)(Al[buf] + idx * 8) = o;
      }
    }
  };

  // prologue: stage tile 0
  if constexpr (F32A) {
    loadA(0);
    writeA(0);
  } else {
    stageA_dma(0, 0);
  }
  stageB(0, 0);

  int cur = 0;
  const int nt = K >> 5;
  for (int t = 0; t < nt; ++t) {
    __syncthreads();  // buf[cur] staged + WAR for buf[cur^1]
    if (t + 1 < nt) {
      stageB(cur ^ 1, (t + 1) * 32);
      if constexpr (F32A)
        loadA((t + 1) * 32);  // issue only; write after MFMA
      else
        stageA_dma(cur ^ 1, (t + 1) * 32);
    }
    bf16x8 fa[4], fb[4];
#pragma unroll
    for (int i = 0; i < 4; ++i) {
      fa[i] = *(const bf16x8*)(Al[cur] + (wr + i * 16 + l15) * 32 + sw);
      fb[i] = *(const bf16x8*)(Bl[cur] + (wc + i * 16 + l15) * 32 + sw);
    }
#pragma unroll
    for (int i = 0; i < 4; ++i)
#pragma unroll
      for (int j = 0; j < 4; ++j)
        acc[i][j] = MFMA16(fb[j], fa[i], acc[i][j]);  // swapped: C^T frags
    if constexpr (F32A) {
      if (t + 1 < nt) writeA(cur ^ 1);  // vmcnt wait lands here, post-MFMA
    }
    cur ^= 1;
  }

  // Epilogue: lane holds row=..+l15, 4 consecutive cols.
#pragma unroll
  for (int i = 0; i < 4; ++i) {
#pragma unroll
    for (int j = 0; j < 4; ++j) {
      int row = m0 + wr + i * 16 + l15;
      int col = n0 + wc + j * 16 + quad * 4;
      size_t off = (size_t)row * N + col;
      f32x4 v = acc[i][j];
      if constexpr (EPI == 1) {
#pragma unroll
        for (int e = 0; e < 4; ++e) v[e] = fmaxf(v[e], 0.f);
      }
      if constexpr (EPI == 2) v += rload(resid + off);
      if constexpr (EPI == 3)
        v += rload(resid + off) + *(const f32x4*)(bias + col);
      cstore(C + off, v);
    }
  }
}

// ---------------------------------------------------------------------------
// Fused LN + FFN: out = relu(LN(x) @ W1) @ W2 + bias + LN(x), per 128-row
// block, dual-path batched via blockIdx.z. All intermediates stay in LDS:
//   Y [128][264] (LN output, also the final residual)        66 KB
//   T [128][264] (relu(Y@W1))                                66 KB
//   Wc [256][40] (current BK=32 weight chunk, reg-prefetched) 20 KB
// Total 152KB -> 1 block/CU. Each GEMM: 8 K-steps x 32 MFMA/wave; weight
// chunks are L2-resident (128KB reused by all blocks). Saves the yf/tf HBM
// round-trips (64MB) and 2 launches vs ln+FFN1+FFN2.
// Wave layout (swapped-operand): wave owns rows w*32..+31; acc[2][16];
// lane -> row = w*32+i*16+l15, cols n = j*16+quad*4..+3 (vectorized I/O).
// ---------------------------------------------------------------------------
struct FArg {
  const bf16* x[2];
  const float* lnw[2];
  const float* lnb[2];
  const bf16* W1T[2];
  const bf16* W2T[2];
  const float* bias[2];
  float* out[2];
  int M[2];
};

__global__ __launch_bounds__(256, 1) void ffn_kernel(FArg g) {
  const int z = blockIdx.z;
  const int m0 = blockIdx.x * 128;
  if (m0 >= g.M[z]) return;
  const int tid = threadIdx.x;
  const int lane = tid & 63;
  const int w = tid >> 6;
  const int l15 = lane & 15, quad = lane >> 4;

  __shared__ __align__(16) bf16 Y[128 * 264];
  __shared__ __align__(16) bf16 T[128 * 264];
  __shared__ __align__(16) bf16 Wc[256 * 40];

  // ---- LN of x tile -> Y (thread = half-row; pair-combine via shfl) ----
  {
    const int row = tid >> 1, c0 = (tid & 1) * 128;
    const bf16* xr = g.x[z] + (size_t)(m0 + row) * 256 + c0;
    bf16x8 v[16];
#pragma unroll
    for (int i = 0; i < 16; ++i) v[i] = *(const bf16x8*)(xr + i * 8);
    float s = 0.f, ss = 0.f;
#pragma unroll
    for (int i = 0; i < 16; ++i)
#pragma unroll
      for (int e = 0; e < 8; ++e) {
        float f = (float)v[i][e];
        s += f;
        ss += f * f;
      }
    s += __shfl_xor(s, 1, 64);
    ss += __shfl_xor(ss, 1, 64);
    float mean = s * (1.f / 256.f);
    float var = ss * (1.f / 256.f) - mean * mean;
    float rstd = rsqrtf(var + 1e-5f);
    const float* wv = g.lnw[z] + c0;
    const float* bv = g.lnb[z] + c0;
    bf16* yr = Y + row * 264 + c0;
#pragma unroll
    for (int i = 0; i < 16; ++i) {
      f32x4 w0 = *(const f32x4*)(wv + i * 8);
      f32x4 w1 = *(const f32x4*)(wv + i * 8 + 4);
      f32x4 b0 = *(const f32x4*)(bv + i * 8);
      f32x4 b1 = *(const f32x4*)(bv + i * 8 + 4);
      bf16x8 o;
#pragma unroll
      for (int e = 0; e < 4; ++e) {
        o[e] = (bf16)(((float)v[i][e] - mean) * rstd * w0[e] + b0[e]);
        o[4 + e] = (bf16)(((float)v[i][4 + e] - mean) * rstd * w1[e] + b1[e]);
      }
      *(bf16x8*)(yr + i * 8) = o;
    }
  }
  __syncthreads();

  f32x4 acc[2][16];
  auto run_gemm = [&](const bf16* SRC, const bf16* WT) {
#pragma unroll
    for (int i = 0; i < 2; ++i)
#pragma unroll
      for (int j = 0; j < 16; ++j) acc[i][j] = (f32x4){0.f, 0.f, 0.f, 0.f};
    bf16x8 wrg[4];
    {
      const bf16* wp = WT + (size_t)tid * 256;
#pragma unroll
      for (int c = 0; c < 4; ++c) wrg[c] = *(const bf16x8*)(wp + c * 8);
    }
    for (int ks = 0; ks < 8; ++ks) {
#pragma unroll
      for (int c = 0; c < 4; ++c)
        *(bf16x8*)(Wc + tid * 40 + c * 8) = wrg[c];
      __syncthreads();
      if (ks < 7) {  // prefetch next chunk; flies under MFMA
        const bf16* wp = WT + (size_t)tid * 256 + (ks + 1) * 32;
#pragma unroll
        for (int c = 0; c < 4; ++c) wrg[c] = *(const bf16x8*)(wp + c * 8);
      }
      bf16x8 fa[2];
#pragma unroll
      for (int i = 0; i < 2; ++i)
        fa[i] = *(const bf16x8*)(SRC + (w * 32 + i * 16 + l15) * 264 +
                                 ks * 32 + quad * 8);
#pragma unroll
      for (int j = 0; j < 16; ++j) {
        bf16x8 fb = *(const bf16x8*)(Wc + (j * 16 + l15) * 40 + quad * 8);
#pragma unroll
        for (int i = 0; i < 2; ++i) acc[i][j] = MFMA16(fb, fa[i], acc[i][j]);
      }
      __syncthreads();  // Wc WAR before next chunk write
    }
  };

  // GEMM1: T = relu(Y @ W1)
  run_gemm(Y, g.W1T[z]);
#pragma unroll
  for (int i = 0; i < 2; ++i)
#pragma unroll
    for (int j = 0; j < 16; ++j) {
      int m = w * 32 + i * 16 + l15;
      int n = j * 16 + quad * 4;
      bf16x4 o;
#pragma unroll
      for (int e = 0; e < 4; ++e) o[e] = (bf16)fmaxf(acc[i][j][e], 0.f);
      *(bf16x4*)(T + m * 264 + n) = o;
    }
  __syncthreads();

  // GEMM2: out = T @ W2 + bias + Y
  run_gemm(T, g.W2T[z]);
  const float* bias = g.bias[z];
  float* out = g.out[z];
#pragma unroll
  for (int i = 0; i < 2; ++i)
#pragma unroll
    for (int j = 0; j < 16; ++j) {
      int m = w * 32 + i * 16 + l15;
      int n = j * 16 + quad * 4;
      bf16x4 yv = *(const bf16x4*)(Y + m * 264 + n);
      f32x4 v = acc[i][j] + *(const f32x4*)(bias + n);
      v[0] += (float)yv[0];
      v[1] += (float)yv[1];
      v[2] += (float)yv[2];
      v[3] += (float)yv[3];
      *(f32x4*)(out + (size_t)(m0 + m) * 256 + n) = v;
    }
}

// ---------------------------------------------------------------------------
// Fused dual-softmax attention (round-6 verified, 95.4us): swapped QK^T with
// register-held P, ones-MFMA colsum, atomic-free partial slabs.
// ---------------------------------------------------------------------------
__global__ __launch_bounds__(256, 1) void attf_kernel(
    const bf16* q, const bf16* __restrict__ kk, const bf16* __restrict__ v1,
    const bf16* __restrict__ v2, bf16* af, float* __restrict__ acc_p,
    float* __restrict__ colsum_p) {
  const int nb = blockIdx.x;  // 4 blocks of 1024 rows
  const int h = blockIdx.y;
  const int b = blockIdx.z;
  const int tid = threadIdx.x;
  const int lane = tid & 63;
  const int w = tid >> 6;
  const int l15 = lane & 15, quad = lane >> 4;

  __shared__ __align__(16) bf16 klds[256 * 72];   // [m][d]        36.0 KB
  __shared__ __align__(16) bf16 v2T[64 * 264];    // [d][m-perm]   33.0 KB
  __shared__ __align__(16) bf16 v1T[2][64 * 72];  // [d][n_local]  18.0 KB
  __shared__ __align__(16) bf16 PT[256 * 72];     // [m][n_local]  36.0 KB

  // ---- prologue: stage K, v2T (perm'd cols), v1T[0]; q frags ch=0 ----
#pragma unroll
  for (int c = 0; c < 8; ++c) {
    int idx = tid + c * 256;  // 0..2047
    int m = idx >> 3;
    int dc = (idx & 7) * 8;
    *(bf16x8*)(klds + m * 72 + dc) =
        *(const bf16x8*)(kk + ((size_t)(b * 256 + m)) * 512 + h * 64 + dc);
  }
#pragma unroll
  for (int c = 0; c < 8; ++c) {
    int idx = tid + c * 256;
    int m = idx >> 3;
    int dc = (idx & 7) * 8;
    bf16x8 t =
        *(const bf16x8*)(v2 + ((size_t)(b * 256 + m)) * 512 + h * 64 + dc);
    // column position p = pi^-1(m) (verified round 3)
    int p = (m & ~31) |
            (((((m >> 2) & 3) << 3) + (m & 3)) + (((m >> 4) & 1) << 2));
#pragma unroll
    for (int j = 0; j < 8; ++j) v2T[(dc + j) * 264 + p] = t[j];
  }
  {
    const int nl = tid >> 3;
    const int dc = (tid & 7) * 8;
    const bf16* v1b =
        v1 + ((size_t)(b * 4096 + nb * 1024)) * 512 + h * 64 + dc;
    bf16x8 t0 = *(const bf16x8*)(v1b + (size_t)nl * 512);
    bf16x8 t1 = *(const bf16x8*)(v1b + (size_t)(nl + 32) * 512);
#pragma unroll
    for (int j = 0; j < 8; ++j) {
      v1T[0][(dc + j) * 72 + nl] = t0[j];
      v1T[0][(dc + j) * 72 + nl + 32] = t1[j];
    }
  }
  bf16x8 qa0, qa1;
  {
    int nrow = b * 4096 + nb * 1024 + w * 16 + l15;
    const bf16* qp = q + (size_t)nrow * 512 + h * 64 + quad * 8;
    qa0 = *(const bf16x8*)(qp);
    qa1 = *(const bf16x8*)(qp + 32);
  }

  f32x4 oc2[16];
#pragma unroll
  for (int i = 0; i < 16; ++i) oc2[i] = (f32x4){0.f, 0.f, 0.f, 0.f};
  f32x4 csa[4];
#pragma unroll
  for (int i = 0; i < 4; ++i) csa[i] = (f32x4){0.f, 0.f, 0.f, 0.f};
  bf16x8 ones8;
#pragma unroll
  for (int j = 0; j < 8; ++j) ones8[j] = (bf16)1.0f;

  __syncthreads();

  for (int ch = 0; ch < 16; ++ch) {
    // ---------------- phase A: QK^T (swapped) + O1 + af ----------------
    bf16x8 v1a, v1b;
    const int nl = tid >> 3;
    const int dc = (tid & 7) * 8;
    if (ch < 15) {
      const bf16* v1p =
          v1 + ((size_t)(b * 4096 + nb * 1024 + (ch + 1) * 64)) * 512 +
          h * 64 + dc;
      v1a = *(const bf16x8*)(v1p + (size_t)nl * 512);
      v1b = *(const bf16x8*)(v1p + (size_t)(nl + 32) * 512);
    }

    bf16x8 pa[8];
    float rs = 0.f;
#pragma unroll
    for (int mt = 0; mt < 16; ++mt) {
      const bf16* kp = klds + (mt * 16 + l15) * 72 + quad * 8;
      bf16x8 ka0 = *(const bf16x8*)(kp);
      bf16x8 ka1 = *(const bf16x8*)(kp + 32);
      f32x4 s = (f32x4){0.f, 0.f, 0.f, 0.f};
      s = MFMA16(ka0, qa0, s);  // swapped: A=K rows m, B=q cols n
      s = MFMA16(ka1, qa1, s);
      float e0 = exp2f(s[0] * CEXP);
      float e1 = exp2f(s[1] * CEXP);
      float e2 = exp2f(s[2] * CEXP);
      float e3 = exp2f(s[3] * CEXP);
      rs += (e0 + e1) + (e2 + e3);
      bf16 b0 = (bf16)e0, b1 = (bf16)e1, b2 = (bf16)e2, b3 = (bf16)e3;
      int mrow = mt * 16 + quad * 4;  // lane's E rows; col n = w*16+l15
      PT[(mrow + 0) * 72 + w * 16 + l15] = b0;
      PT[(mrow + 1) * 72 + w * 16 + l15] = b1;
      PT[(mrow + 2) * 72 + w * 16 + l15] = b2;
      PT[(mrow + 3) * 72 + w * 16 + l15] = b3;
      pa[mt >> 1][(mt & 1) * 4 + 0] = b0;
      pa[mt >> 1][(mt & 1) * 4 + 1] = b1;
      pa[mt >> 1][(mt & 1) * 4 + 2] = b2;
      pa[mt >> 1][(mt & 1) * 4 + 3] = b3;
    }

    // O1 = P @ v2 (A=v2T perm'd, B=pa from regs; lane->[n=l15][4 consec d])
    f32x4 o1[4];
#pragma unroll
    for (int i = 0; i < 4; ++i) o1[i] = (f32x4){0.f, 0.f, 0.f, 0.f};
#pragma unroll
    for (int ks = 0; ks < 8; ++ks) {
#pragma unroll
      for (int dt = 0; dt < 4; ++dt) {
        bf16x8 vb = *(const bf16x8*)(v2T + (dt * 16 + l15) * 264 + ks * 32 +
                                     quad * 8);
        o1[dt] = MFMA16(vb, pa[ks], o1[dt]);
      }
    }
    {
      float rsf = rs + __shfl_xor(rs, 16, 64);
      rsf += __shfl_xor(rsf, 32, 64);
      float inv = 1.f / rsf;
      int n = nb * 1024 + ch * 64 + w * 16 + l15;
      bf16* ap = af + ((size_t)(b * 4096 + n)) * 512 + h * 64 + quad * 4;
#pragma unroll
      for (int dt = 0; dt < 4; ++dt) {
        bf16x4 ov;
        ov[0] = (bf16)(o1[dt][0] * inv);
        ov[1] = (bf16)(o1[dt][1] * inv);
        ov[2] = (bf16)(o1[dt][2] * inv);
        ov[3] = (bf16)(o1[dt][3] * inv);
        *(bf16x4*)(ap + dt * 16) = ov;
      }
    }

    if (ch < 15) {
      bf16* dst = v1T[(ch + 1) & 1];
#pragma unroll
      for (int j = 0; j < 8; ++j) {
        dst[(dc + j) * 72 + nl] = v1a[j];
        dst[(dc + j) * 72 + nl + 32] = v1b[j];
      }
    }
    __syncthreads();  // PT (+next v1T) ready

    // ---------------- phase B: O2 + colsum-MFMA ----------------
    bf16x8 qn0 = qa0, qn1 = qa1;
    if (ch < 15) {
      int nrow = b * 4096 + nb * 1024 + (ch + 1) * 64 + w * 16 + l15;
      const bf16* qp = q + (size_t)nrow * 512 + h * 64 + quad * 8;
      qn0 = *(const bf16x8*)(qp);
      qn1 = *(const bf16x8*)(qp + 32);
    }

    const bf16* vc = v1T[ch & 1];
#pragma unroll
    for (int ks = 0; ks < 2; ++ks) {
      bf16x8 vbv[4];
#pragma unroll
      for (int dt = 0; dt < 4; ++dt)
        vbv[dt] = *(const bf16x8*)(vc + (dt * 16 + l15) * 72 + ks * 32 +
                                   quad * 8);
#pragma unroll
      for (int mq = 0; mq < 4; ++mq) {
        bf16x8 pa2 = *(const bf16x8*)(PT + (mq * 64 + w * 16 + l15) * 72 +
                                      ks * 32 + quad * 8);
#pragma unroll
        for (int dt = 0; dt < 4; ++dt)
          oc2[mq * 4 + dt] = MFMA16(vbv[dt], pa2, oc2[mq * 4 + dt]);
        csa[mq] = MFMA16(pa2, ones8, csa[mq]);  // colsum over n (ones-MFMA)
      }
    }
    __syncthreads();  // WAR: PT/v1T reads done before next ch restage
    qa0 = qn0;
    qa1 = qn1;
  }

  // ---- epilogue: per-block partial slabs indexed by nb ----
  const size_t slab = (size_t)(nb * 64 + b * 8 + h);
  if (l15 == 0) {
#pragma unroll
    for (int mq = 0; mq < 4; ++mq)
#pragma unroll
      for (int r = 0; r < 4; ++r)
        colsum_p[slab * 256 + mq * 64 + w * 16 + quad * 4 + r] = csa[mq][r];
  }
  float* base = acc_p + slab * (256 * 64);
#pragma unroll
  for (int mq = 0; mq < 4; ++mq) {
    int m = mq * 64 + w * 16 + l15;
#pragma unroll
    for (int dt = 0; dt < 4; ++dt)
      *(f32x4*)(base + m * 64 + dt * 16 + quad * 4) = oc2[mq * 4 + dt];
  }
}

// ---------------------------------------------------------------------------
// acm[b][m][h*64+d] = sum_p acc_p[p][b][h][m][d] / sum_p colsum_p[p][b][h][m]
// ---------------------------------------------------------------------------
__global__ __launch_bounds__(256) void acm_kernel(
    const float* __restrict__ acc_p, const float* __restrict__ colsum_p,
    bf16* __restrict__ acm) {
  int idx = blockIdx.x * 256 + threadIdx.x;  // 8*256*512 total
  int d = idx & 63;
  int h = (idx >> 6) & 7;
  int m = (idx >> 9) & 255;
  int b = idx >> 17;
  float cv = 0.f, v = 0.f;
#pragma unroll
  for (int p = 0; p < 4; ++p) {
    cv += colsum_p[((size_t)(p * 64 + b * 8 + h)) * 256 + m];
    v += acc_p[(((size_t)(p * 64 + b * 8 + h)) * 256 + m) * 64 + d];
  }
  acm[idx] = (bf16)(v / cv);
}

// ---------------------------------------------------------------------------
extern "C" void kernel_launch(void* const* d_in, const int* in_sizes, int n_in,
                              void* d_out, int out_size, void* d_ws,
                              size_t ws_size, hipStream_t stream) {
  const float* feat = (const float*)d_in[0];
  const float* center = (const float*)d_in[1];
  const float* pos = (const float*)d_in[2];
  const float* cpos = (const float*)d_in[3];
  const float* Wq = (const float*)d_in[4];
  const float* Wk = (const float*)d_in[5];
  const float* Wv1 = (const float*)d_in[6];
  const float* Wv2 = (const float*)d_in[7];
  const float* Wo1 = (const float*)d_in[8];
  const float* Wo2 = (const float*)d_in[9];
  const float* ln1w = (const float*)d_in[10];
  const float* ln1b = (const float*)d_in[11];
  const float* ln2w = (const float*)d_in[12];
  const float* ln2b = (const float*)d_in[13];
  const float* f1W1 = (const float*)d_in[14];
  const float* f1W2 = (const float*)d_in[15];
  const float* f1b2 = (const float*)d_in[16];
  const float* f2W1 = (const float*)d_in[17];
  const float* f2W2 = (const float*)d_in[18];
  const float* f2b2 = (const float*)d_in[19];

  char* ws = (char*)d_ws;
  const size_t MB = 1024 * 1024;
  // workspace layout (~94 MB). af aliases q; acc partials alias xq (dead
  // after q GEMM); acm aliases v2 (dead after attf).
  bf16* q_ = (bf16*)(ws + 0);           // 32MB [32768,512]
  bf16* af_ = q_;                       // alias (see attf_kernel note)
  bf16* v1_ = (bf16*)(ws + 32 * MB);    // 32MB [32768,512]
  bf16* xq_ = (bf16*)(ws + 64 * MB);    // 16MB [32768,256]
  float* accp_ = (float*)(ws + 64 * MB);  // alias: 16MB fp32 [4,8,8,256,64]
  bf16* rf_ = xq_;                      // alias after acm (Wo1 GEMM output)
  bf16* k_ = (bf16*)(ws + 80 * MB);     // 2MB [2048,512]
  bf16* rc_ = (bf16*)(ws + 82 * MB);    // 1MB [2048,256]
  bf16* v2_ = (bf16*)(ws + 83 * MB);    // 2MB [2048,512]
  bf16* acm_ = v2_;                     // alias after attf
  float* colsum_ = (float*)(ws + 89 * MB);     // 256KB fp32 [4,8,8,256]
  bf16* wt_ = (bf16*)(ws + 89 * MB + 262144);  // 2MB transposed weights

  bf16* WqT = wt_;
  bf16* WkT = WqT + 131072;
  bf16* Wv1T = WkT + 131072;
  bf16* Wv2T = Wv1T + 131072;
  bf16* Wo1T = Wv2T + 131072;
  bf16* Wo2T = Wo1T + 131072;
  bf16* f1W1T = Wo2T + 131072;
  bf16* f1W2T = f1W1T + 65536;
  bf16* f2W1T = f1W2T + 65536;
  bf16* f2W2T = f2W1T + 65536;

  float* out_feat = (float*)d_out;
  float* out_center = out_feat + (size_t)8 * 4096 * 256;

  WTArgs wa;
  const float* srcs[10] = {Wq, Wk, Wv1, Wv2, Wo1, Wo2, f1W1, f1W2, f2W1, f2W2};
  bf16* dsts[10] = {WqT, WkT, Wv1T, Wv2T, Wo1T, Wo2T, f1W1T, f1W2T, f2W1T, f2W2T};
  int Ks[10] = {256, 256, 256, 256, 512, 512, 256, 256, 256, 256};
  int Ns[10] = {512, 512, 512, 512, 256, 256, 256, 256, 256, 256};
  for (int i = 0; i < 10; ++i) {
    wa.src[i] = srcs[i];
    wa.dst[i] = dsts[i];
    wa.K[i] = Ks[i];
    wa.N[i] = Ns[i];
  }

  wtrans_kernel<<<dim3(8, 8, 10), 256, 0, stream>>>(wa);
  prep_xq_kernel<<<dim3(64, 4, 8), 256, 0, stream>>>(feat, pos, xq_);

  // q projection
  {
    GArg a{};
    a.A[0] = xq_; a.BT[0] = WqT; a.C[0] = q_; a.M[0] = 32768;
    gemm_kernel<0, bf16, bf16, bf16, false>
        <<<dim3(256, 4, 1), 256, 0, stream>>>(a, 512, 256);
  }
  // k projection with fused (center + cpos) add
  {
    GArg a{};
    a.A[0] = center; a.A2[0] = cpos; a.BT[0] = WkT; a.C[0] = k_;
    a.M[0] = 2048;
    gemm_kernel<0, bf16, bf16, float, true>
        <<<dim3(16, 4, 1), 256, 0, stream>>>(a, 512, 256);
  }
  // v1 + v2 projections (batched, fp32 A, async-split staging)
  {
    GArg a{};
    a.A[0] = feat; a.A[1] = center;
    a.BT[0] = Wv1T; a.BT[1] = Wv2T;
    a.C[0] = v1_; a.C[1] = v2_;
    a.M[0] = 32768; a.M[1] = 2048;
    gemm_kernel<0, bf16, bf16, float, false>
        <<<dim3(256, 4, 2), 256, 0, stream>>>(a, 512, 256);
  }

  // fused dual-softmax attention (atomic-free partials)
  attf_kernel<<<dim3(4, 8, 8), 256, 0, stream>>>(q_, k_, v1_, v2_, af_, accp_,
                                                 colsum_);
  acm_kernel<<<dim3(4096), 256, 0, stream>>>(accp_, colsum_, acm_);

  // Wo1 + Wo2 (batched, +resid)
  {
    GArg a{};
    a.A[0] = af_; a.A[1] = acm_;
    a.BT[0] = Wo1T; a.BT[1] = Wo2T;
    a.C[0] = rf_; a.C[1] = rc_;
    a.resid[0] = feat; a.resid[1] = center;
    a.M[0] = 32768; a.M[1] = 2048;
    gemm_kernel<2, bf16, float, bf16, false>
        <<<dim3(256, 2, 2), 256, 0, stream>>>(a, 256, 512);
  }
  // fused LN + FFN (both paths)
  {
    FArg f{};
    f.x[0] = rf_; f.x[1] = rc_;
    f.lnw[0] = ln1w; f.lnb[0] = ln1b;
    f.lnw[1] = ln2w; f.lnb[1] = ln2b;
    f.W1T[0] = f1W1T; f.W1T[1] = f2W1T;
    f.W2T[0] = f1W2T; f.W2T[1] = f2W2T;
    f.bias[0] = f1b2; f.bias[1] = f2b2;
    f.out[0] = out_feat; f.out[1] = out_center;
    f.M[0] = 32768; f.M[1] = 2048;
    ffn_kernel<<<dim3(256, 1, 2), 256, 0, stream>>>(f);
  }
}

// Round 8
// 354.734 us; speedup vs baseline: 1.0468x; 1.0468x over previous
//
#include <hip/hip_runtime.h>

typedef __bf16 bf16;
typedef __bf16 bf16x4 __attribute__((ext_vector_type(4)));
typedef __bf16 bf16x8 __attribute__((ext_vector_type(8)));
typedef float f32x4 __attribute__((ext_vector_type(4)));

#define MFMA16(a, b, c) __builtin_amdgcn_mfma_f32_16x16x32_bf16(a, b, c, 0, 0, 0)

// Problem constants: B=8, N=4096, M=256, DIM=256, HEADS=8, DIM_HEAD=64, INNER=512
// exp(S*scale) = exp2(S * 0.125 * log2(e))
#define CEXP 0.18033688011112042f

// ---------------------------------------------------------------------------
// Weight pre-transpose + downcast: W[K,N] fp32 -> WT[N,K] bf16 (10 matrices)
// ---------------------------------------------------------------------------
struct WTArgs {
  const float* src[10];
  bf16* dst[10];
  int K[10];
  int N[10];
};

__global__ __launch_bounds__(256) void wtrans_kernel(WTArgs args) {
  const int z = blockIdx.z;
  const int K = args.K[z], N = args.N[z];
  const int k0 = blockIdx.x * 64, n0 = blockIdx.y * 64;
  if (k0 >= K || n0 >= N) return;
  __shared__ float t[64][65];
  const int tx = threadIdx.x & 63, ty = threadIdx.x >> 6;
  const float* __restrict__ src = args.src[z];
  bf16* __restrict__ dst = args.dst[z];
#pragma unroll
  for (int i = 0; i < 16; ++i)
    t[ty + i * 4][tx] = src[(size_t)(k0 + ty + i * 4) * N + n0 + tx];
  __syncthreads();
#pragma unroll
  for (int i = 0; i < 16; ++i)
    dst[(size_t)(n0 + ty + i * 4) * K + k0 + tx] = (bf16)t[tx][ty + i * 4];
}

// ---------------------------------------------------------------------------
// xq[b][n][c] = feat[b][n][c] + pos[b][c][n]  (fp32 in, bf16 out)
// ---------------------------------------------------------------------------
__global__ __launch_bounds__(256) void prep_xq_kernel(
    const float* __restrict__ feat, const float* __restrict__ pos,
    bf16* __restrict__ xq) {
  const int n0 = blockIdx.x * 64;
  const int c0 = blockIdx.y * 64;
  const int b = blockIdx.z;
  __shared__ float t[64][65];
  const int tx = threadIdx.x & 63, ty = threadIdx.x >> 6;
#pragma unroll
  for (int i = 0; i < 16; ++i) {
    int c = ty + i * 4;
    t[c][tx] = pos[((size_t)b * 256 + c0 + c) * 4096 + n0 + tx];
  }
  __syncthreads();
#pragma unroll
  for (int i = 0; i < 16; ++i) {
    int n = ty + i * 4;
    size_t off = ((size_t)b * 4096 + n0 + n) * 256 + c0 + tx;
    xq[off] = (bf16)(feat[off] + t[tx][n]);
  }
}

// ---------------------------------------------------------------------------
// Staging helper: bf16 async DMA global->LDS (16B/lane, linear dest).
// ---------------------------------------------------------------------------
__device__ inline void stage16(const bf16* g, bf16* l) {
  __builtin_amdgcn_global_load_lds(
      (const __attribute__((address_space(1))) void*)g,
      (__attribute__((address_space(3))) void*)l, 16, 0, 0);
}

// Epilogue helpers: vectorized resid load / C store.
__device__ inline f32x4 rload(const float* p) { return *(const f32x4*)p; }
__device__ inline f32x4 rload(const bf16* p) {
  bf16x4 t = *(const bf16x4*)p;
  return (f32x4){(float)t[0], (float)t[1], (float)t[2], (float)t[3]};
}
__device__ inline void cstore(float* p, f32x4 v) { *(f32x4*)p = v; }
__device__ inline void cstore(bf16* p, f32x4 v) {
  bf16x4 o;
  o[0] = (bf16)v[0]; o[1] = (bf16)v[1]; o[2] = (bf16)v[2]; o[3] = (bf16)v[3];
  *(bf16x4*)p = o;
}

// ---------------------------------------------------------------------------
// Generic GEMM, dual-problem batched via blockIdx.z. C[M,N] = A[M,K] @ B[K,N],
// B pre-transposed BT[N,K]. 128x128 tile, 4 waves, BK=32, double-buffered,
// one barrier per K-step (DMA for t+1 flies under MFMA of t).
// fp32-A path uses T14 async-split: issue global loads after barrier, MFMA,
// THEN cvt+ds_write (the vmcnt wait lands after the MFMA block, not before).
// SWAPPED-OPERAND MFMA -> vectorized epilogue. FUSE2: A=A+A2 (fp32 only).
// EPI: 0=none, 1=relu, 2=+resid, 3=+bias+resid.
// ---------------------------------------------------------------------------
struct GArg {
  const void* A[2];
  const void* A2[2];
  const bf16* BT[2];
  void* C[2];
  const void* resid[2];
  const float* bias[2];
  int M[2];
};

template <int EPI, typename TO, typename TR, typename TA, bool FUSE2>
__global__ __launch_bounds__(256) void gemm_kernel(GArg g, int N, int K) {
  const int z = blockIdx.z;
  const int m0 = blockIdx.x * 128;
  if (m0 >= g.M[z]) return;
  constexpr bool F32A = sizeof(TA) == 4;
  const TA* A = (const TA*)g.A[z];
  const TA* A2 = (const TA*)g.A2[z];
  const bf16* BT = g.BT[z];
  TO* C = (TO*)g.C[z];
  const TR* resid = (const TR*)g.resid[z];
  const float* bias = g.bias[z];

  const int n0 = blockIdx.y * 128;
  const int tid = threadIdx.x;
  const int lane = tid & 63;
  const int w = tid >> 6;
  const int wr = (w >> 1) * 64, wc = (w & 1) * 64;
  const int l15 = lane & 15, quad = lane >> 4;

  __shared__ __align__(16) bf16 Al[2][128 * 32];  // 16KB (dbuf)
  __shared__ __align__(16) bf16 Bl[2][128 * 32];  // 16KB

  f32x4 acc[4][4];
#pragma unroll
  for (int i = 0; i < 4; ++i)
#pragma unroll
    for (int j = 0; j < 4; ++j) acc[i][j] = (f32x4){0.f, 0.f, 0.f, 0.f};

  const int sw = (((l15 >> 1) & 3) ^ quad) * 8;  // read-side swizzled granule

  f32x4 ar[2][2], ar2[2][2];  // fp32-A staging regs (A, optional A2)

  auto stageB = [&](int buf, int k0) {
#pragma unroll
    for (int c = 0; c < 2; ++c) {
      int idx = tid + c * 256;
      int row = idx >> 2;
      int gs = ((idx & 3) ^ ((row >> 1) & 3)) * 8;
      stage16(BT + (size_t)(n0 + row) * K + k0 + gs, Bl[buf] + idx * 8);
    }
  };
  auto stageA_dma = [&](int buf, int k0) {
    if constexpr (!F32A) {
#pragma unroll
      for (int c = 0; c < 2; ++c) {
        int idx = tid + c * 256;
        int row = idx >> 2;
        int gs = ((idx & 3) ^ ((row >> 1) & 3)) * 8;
        stage16((const bf16*)A + (size_t)(m0 + row) * K + k0 + gs,
                Al[buf] + idx * 8);
      }
    }
  };
  auto loadA = [&](int k0) {
    if constexpr (F32A) {
      const float* Af = (const float*)(const void*)A;
      const float* A2f = (const float*)(const void*)A2;
#pragma unroll
      for (int c = 0; c < 2; ++c) {
        int idx = tid + c * 256;
        int row = idx >> 2;
        int gs = ((idx & 3) ^ ((row >> 1) & 3)) * 8;
        const float* p = Af + (size_t)(m0 + row) * K + k0 + gs;
        ar[c][0] = *(const f32x4*)p;
        ar[c][1] = *((const f32x4*)p + 1);
        if constexpr (FUSE2) {
          const float* p2 = A2f + (size_t)(m0 + row) * K + k0 + gs;
          ar2[c][0] = *(const f32x4*)p2;
          ar2[c][1] = *((const f32x4*)p2 + 1);
        }
      }
    }
  };
  auto writeA = [&](int buf) {
    if constexpr (F32A) {
#pragma unroll
      for (int c = 0; c < 2; ++c) {
        int idx = tid + c * 256;
        f32x4 u = ar[c][0], v = ar[c][1];
        if constexpr (FUSE2) {
          u += ar2[c][0];
          v += ar2[c][1];
        }
        bf16x8 o;
#pragma unroll
        for (int e = 0; e < 4; ++e) {
          o[e] = (bf16)u[e];
          o[4 + e] = (bf16)v[e];
        }
        *(bf16x8*)(Al[buf] + idx * 8) = o;
      }
    }
  };

  // prologue: stage tile 0
  if constexpr (F32A) {
    loadA(0);
    writeA(0);
  } else {
    stageA_dma(0, 0);
  }
  stageB(0, 0);

  int cur = 0;
  const int nt = K >> 5;
  for (int t = 0; t < nt; ++t) {
    __syncthreads();  // buf[cur] staged + WAR for buf[cur^1]
    if (t + 1 < nt) {
      stageB(cur ^ 1, (t + 1) * 32);
      if constexpr (F32A)
        loadA((t + 1) * 32);  // issue only; write after MFMA
      else
        stageA_dma(cur ^ 1, (t + 1) * 32);
    }
    bf16x8 fa[4], fb[4];
#pragma unroll
    for (int i = 0; i < 4; ++i) {
      fa[i] = *(const bf16x8*)(Al[cur] + (wr + i * 16 + l15) * 32 + sw);
      fb[i] = *(const bf16x8*)(Bl[cur] + (wc + i * 16 + l15) * 32 + sw);
    }
#pragma unroll
    for (int i = 0; i < 4; ++i)
#pragma unroll
      for (int j = 0; j < 4; ++j)
        acc[i][j] = MFMA16(fb[j], fa[i], acc[i][j]);  // swapped: C^T frags
    if constexpr (F32A) {
      if (t + 1 < nt) writeA(cur ^ 1);  // vmcnt wait lands here, post-MFMA
    }
    cur ^= 1;
  }

  // Epilogue: lane holds row=..+l15, 4 consecutive cols.
#pragma unroll
  for (int i = 0; i < 4; ++i) {
#pragma unroll
    for (int j = 0; j < 4; ++j) {
      int row = m0 + wr + i * 16 + l15;
      int col = n0 + wc + j * 16 + quad * 4;
      size_t off = (size_t)row * N + col;
      f32x4 v = acc[i][j];
      if constexpr (EPI == 1) {
#pragma unroll
        for (int e = 0; e < 4; ++e) v[e] = fmaxf(v[e], 0.f);
      }
      if constexpr (EPI == 2) v += rload(resid + off);
      if constexpr (EPI == 3)
        v += rload(resid + off) + *(const f32x4*)(bias + col);
      cstore(C + off, v);
    }
  }
}

// ---------------------------------------------------------------------------
// Fused dual-softmax attention (verified r6/r7): swapped QK^T with
// register-held P, ones-MFMA colsum, atomic-free partial slabs.
// ---------------------------------------------------------------------------
__global__ __launch_bounds__(256, 1) void attf_kernel(
    const bf16* q, const bf16* __restrict__ kk, const bf16* __restrict__ v1,
    const bf16* __restrict__ v2, bf16* af, float* __restrict__ acc_p,
    float* __restrict__ colsum_p) {
  const int nb = blockIdx.x;  // 4 blocks of 1024 rows
  const int h = blockIdx.y;
  const int b = blockIdx.z;
  const int tid = threadIdx.x;
  const int lane = tid & 63;
  const int w = tid >> 6;
  const int l15 = lane & 15, quad = lane >> 4;

  __shared__ __align__(16) bf16 klds[256 * 72];   // [m][d]        36.0 KB
  __shared__ __align__(16) bf16 v2T[64 * 264];    // [d][m-perm]   33.0 KB
  __shared__ __align__(16) bf16 v1T[2][64 * 72];  // [d][n_local]  18.0 KB
  __shared__ __align__(16) bf16 PT[256 * 72];     // [m][n_local]  36.0 KB

  // ---- prologue: stage K, v2T (perm'd cols), v1T[0]; q frags ch=0 ----
#pragma unroll
  for (int c = 0; c < 8; ++c) {
    int idx = tid + c * 256;  // 0..2047
    int m = idx >> 3;
    int dc = (idx & 7) * 8;
    *(bf16x8*)(klds + m * 72 + dc) =
        *(const bf16x8*)(kk + ((size_t)(b * 256 + m)) * 512 + h * 64 + dc);
  }
#pragma unroll
  for (int c = 0; c < 8; ++c) {
    int idx = tid + c * 256;
    int m = idx >> 3;
    int dc = (idx & 7) * 8;
    bf16x8 t =
        *(const bf16x8*)(v2 + ((size_t)(b * 256 + m)) * 512 + h * 64 + dc);
    // column position p = pi^-1(m) (verified round 3)
    int p = (m & ~31) |
            (((((m >> 2) & 3) << 3) + (m & 3)) + (((m >> 4) & 1) << 2));
#pragma unroll
    for (int j = 0; j < 8; ++j) v2T[(dc + j) * 264 + p] = t[j];
  }
  {
    const int nl = tid >> 3;
    const int dc = (tid & 7) * 8;
    const bf16* v1b =
        v1 + ((size_t)(b * 4096 + nb * 1024)) * 512 + h * 64 + dc;
    bf16x8 t0 = *(const bf16x8*)(v1b + (size_t)nl * 512);
    bf16x8 t1 = *(const bf16x8*)(v1b + (size_t)(nl + 32) * 512);
#pragma unroll
    for (int j = 0; j < 8; ++j) {
      v1T[0][(dc + j) * 72 + nl] = t0[j];
      v1T[0][(dc + j) * 72 + nl + 32] = t1[j];
    }
  }
  bf16x8 qa0, qa1;
  {
    int nrow = b * 4096 + nb * 1024 + w * 16 + l15;
    const bf16* qp = q + (size_t)nrow * 512 + h * 64 + quad * 8;
    qa0 = *(const bf16x8*)(qp);
    qa1 = *(const bf16x8*)(qp + 32);
  }

  f32x4 oc2[16];
#pragma unroll
  for (int i = 0; i < 16; ++i) oc2[i] = (f32x4){0.f, 0.f, 0.f, 0.f};
  f32x4 csa[4];
#pragma unroll
  for (int i = 0; i < 4; ++i) csa[i] = (f32x4){0.f, 0.f, 0.f, 0.f};
  bf16x8 ones8;
#pragma unroll
  for (int j = 0; j < 8; ++j) ones8[j] = (bf16)1.0f;

  __syncthreads();

  for (int ch = 0; ch < 16; ++ch) {
    // ---------------- phase A: QK^T (swapped) + O1 + af ----------------
    bf16x8 v1a, v1b;
    const int nl = tid >> 3;
    const int dc = (tid & 7) * 8;
    if (ch < 15) {
      const bf16* v1p =
          v1 + ((size_t)(b * 4096 + nb * 1024 + (ch + 1) * 64)) * 512 +
          h * 64 + dc;
      v1a = *(const bf16x8*)(v1p + (size_t)nl * 512);
      v1b = *(const bf16x8*)(v1p + (size_t)(nl + 32) * 512);
    }

    bf16x8 pa[8];
    float rs = 0.f;
#pragma unroll
    for (int mt = 0; mt < 16; ++mt) {
      const bf16* kp = klds + (mt * 16 + l15) * 72 + quad * 8;
      bf16x8 ka0 = *(const bf16x8*)(kp);
      bf16x8 ka1 = *(const bf16x8*)(kp + 32);
      f32x4 s = (f32x4){0.f, 0.f, 0.f, 0.f};
      s = MFMA16(ka0, qa0, s);  // swapped: A=K rows m, B=q cols n
      s = MFMA16(ka1, qa1, s);
      float e0 = exp2f(s[0] * CEXP);
      float e1 = exp2f(s[1] * CEXP);
      float e2 = exp2f(s[2] * CEXP);
      float e3 = exp2f(s[3] * CEXP);
      rs += (e0 + e1) + (e2 + e3);
      bf16 b0 = (bf16)e0, b1 = (bf16)e1, b2 = (bf16)e2, b3 = (bf16)e3;
      int mrow = mt * 16 + quad * 4;  // lane's E rows; col n = w*16+l15
      PT[(mrow + 0) * 72 + w * 16 + l15] = b0;
      PT[(mrow + 1) * 72 + w * 16 + l15] = b1;
      PT[(mrow + 2) * 72 + w * 16 + l15] = b2;
      PT[(mrow + 3) * 72 + w * 16 + l15] = b3;
      pa[mt >> 1][(mt & 1) * 4 + 0] = b0;
      pa[mt >> 1][(mt & 1) * 4 + 1] = b1;
      pa[mt >> 1][(mt & 1) * 4 + 2] = b2;
      pa[mt >> 1][(mt & 1) * 4 + 3] = b3;
    }

    // O1 = P @ v2 (A=v2T perm'd, B=pa from regs; lane->[n=l15][4 consec d])
    f32x4 o1[4];
#pragma unroll
    for (int i = 0; i < 4; ++i) o1[i] = (f32x4){0.f, 0.f, 0.f, 0.f};
#pragma unroll
    for (int ks = 0; ks < 8; ++ks) {
#pragma unroll
      for (int dt = 0; dt < 4; ++dt) {
        bf16x8 vb = *(const bf16x8*)(v2T + (dt * 16 + l15) * 264 + ks * 32 +
                                     quad * 8);
        o1[dt] = MFMA16(vb, pa[ks], o1[dt]);
      }
    }
    {
      float rsf = rs + __shfl_xor(rs, 16, 64);
      rsf += __shfl_xor(rsf, 32, 64);
      float inv = 1.f / rsf;
      int n = nb * 1024 + ch * 64 + w * 16 + l15;
      bf16* ap = af + ((size_t)(b * 4096 + n)) * 512 + h * 64 + quad * 4;
#pragma unroll
      for (int dt = 0; dt < 4; ++dt) {
        bf16x4 ov;
        ov[0] = (bf16)(o1[dt][0] * inv);
        ov[1] = (bf16)(o1[dt][1] * inv);
        ov[2] = (bf16)(o1[dt][2] * inv);
        ov[3] = (bf16)(o1[dt][3] * inv);
        *(bf16x4*)(ap + dt * 16) = ov;
      }
    }

    if (ch < 15) {
      bf16* dst = v1T[(ch + 1) & 1];
#pragma unroll
      for (int j = 0; j < 8; ++j) {
        dst[(dc + j) * 72 + nl] = v1a[j];
        dst[(dc + j) * 72 + nl + 32] = v1b[j];
      }
    }
    __syncthreads();  // PT (+next v1T) ready

    // ---------------- phase B: O2 + colsum-MFMA ----------------
    bf16x8 qn0 = qa0, qn1 = qa1;
    if (ch < 15) {
      int nrow = b * 4096 + nb * 1024 + (ch + 1) * 64 + w * 16 + l15;
      const bf16* qp = q + (size_t)nrow * 512 + h * 64 + quad * 8;
      qn0 = *(const bf16x8*)(qp);
      qn1 = *(const bf16x8*)(qp + 32);
    }

    const bf16* vc = v1T[ch & 1];
#pragma unroll
    for (int ks = 0; ks < 2; ++ks) {
      bf16x8 vbv[4];
#pragma unroll
      for (int dt = 0; dt < 4; ++dt)
        vbv[dt] = *(const bf16x8*)(vc + (dt * 16 + l15) * 72 + ks * 32 +
                                   quad * 8);
#pragma unroll
      for (int mq = 0; mq < 4; ++mq) {
        bf16x8 pa2 = *(const bf16x8*)(PT + (mq * 64 + w * 16 + l15) * 72 +
                                      ks * 32 + quad * 8);
#pragma unroll
        for (int dt = 0; dt < 4; ++dt)
          oc2[mq * 4 + dt] = MFMA16(vbv[dt], pa2, oc2[mq * 4 + dt]);
        csa[mq] = MFMA16(pa2, ones8, csa[mq]);  // colsum over n (ones-MFMA)
      }
    }
    __syncthreads();  // WAR: PT/v1T reads done before next ch restage
    qa0 = qn0;
    qa1 = qn1;
  }

  // ---- epilogue: per-block partial slabs indexed by nb ----
  const size_t slab = (size_t)(nb * 64 + b * 8 + h);
  if (l15 == 0) {
#pragma unroll
    for (int mq = 0; mq < 4; ++mq)
#pragma unroll
      for (int r = 0; r < 4; ++r)
        colsum_p[slab * 256 + mq * 64 + w * 16 + quad * 4 + r] = csa[mq][r];
  }
  float* base = acc_p + slab * (256 * 64);
#pragma unroll
  for (int mq = 0; mq < 4; ++mq) {
    int m = mq * 64 + w * 16 + l15;
#pragma unroll
    for (int dt = 0; dt < 4; ++dt)
      *(f32x4*)(base + m * 64 + dt * 16 + quad * 4) = oc2[mq * 4 + dt];
  }
}

// ---------------------------------------------------------------------------
// acm[b][m][h*64+d] = sum_p acc_p[p][b][h][m][d] / sum_p colsum_p[p][b][h][m]
// ---------------------------------------------------------------------------
__global__ __launch_bounds__(256) void acm_kernel(
    const float* __restrict__ acc_p, const float* __restrict__ colsum_p,
    bf16* __restrict__ acm) {
  int idx = blockIdx.x * 256 + threadIdx.x;  // 8*256*512 total
  int d = idx & 63;
  int h = (idx >> 6) & 7;
  int m = (idx >> 9) & 255;
  int b = idx >> 17;
  float cv = 0.f, v = 0.f;
#pragma unroll
  for (int p = 0; p < 4; ++p) {
    cv += colsum_p[((size_t)(p * 64 + b * 8 + h)) * 256 + m];
    v += acc_p[(((size_t)(p * 64 + b * 8 + h)) * 256 + m) * 64 + d];
  }
  acm[idx] = (bf16)(v / cv);
}

// ---------------------------------------------------------------------------
// LayerNorm over last dim (256), dual-problem batched by row range.
// ---------------------------------------------------------------------------
__global__ __launch_bounds__(256) void ln_kernel(
    const bf16* __restrict__ x0, const bf16* __restrict__ x1,
    const float* __restrict__ w0, const float* __restrict__ b0,
    const float* __restrict__ w1, const float* __restrict__ b1,
    bf16* __restrict__ y0, bf16* __restrict__ y1, int rows0, int rows1) {
  int wave = threadIdx.x >> 6;
  int lane = threadIdx.x & 63;
  int row = blockIdx.x * 4 + wave;
  const bf16* x;
  const float *wv, *bv;
  bf16* y;
  if (row < rows0) {
    x = x0; wv = w0; bv = b0; y = y0;
  } else {
    row -= rows0;
    if (row >= rows1) return;
    x = x1; wv = w1; bv = b1; y = y1;
  }
  const bf16* xr = x + (size_t)row * 256;
  bf16x4 v = *(const bf16x4*)(xr + lane * 4);
  float f0 = v[0], f1 = v[1], f2 = v[2], f3 = v[3];
  float s = f0 + f1 + f2 + f3;
  float ss = f0 * f0 + f1 * f1 + f2 * f2 + f3 * f3;
#pragma unroll
  for (int m = 1; m < 64; m <<= 1) {
    s += __shfl_xor(s, m, 64);
    ss += __shfl_xor(ss, m, 64);
  }
  float mean = s * (1.f / 256.f);
  float var = ss * (1.f / 256.f) - mean * mean;
  float rstd = rsqrtf(var + 1e-5f);
  f32x4 wq = *(const f32x4*)(wv + lane * 4);
  f32x4 bq = *(const f32x4*)(bv + lane * 4);
  bf16x4 o;
  o[0] = (bf16)((f0 - mean) * rstd * wq[0] + bq[0]);
  o[1] = (bf16)((f1 - mean) * rstd * wq[1] + bq[1]);
  o[2] = (bf16)((f2 - mean) * rstd * wq[2] + bq[2]);
  o[3] = (bf16)((f3 - mean) * rstd * wq[3] + bq[3]);
  *(bf16x4*)(y + (size_t)row * 256 + lane * 4) = o;
}

// ---------------------------------------------------------------------------
extern "C" void kernel_launch(void* const* d_in, const int* in_sizes, int n_in,
                              void* d_out, int out_size, void* d_ws,
                              size_t ws_size, hipStream_t stream) {
  const float* feat = (const float*)d_in[0];
  const float* center = (const float*)d_in[1];
  const float* pos = (const float*)d_in[2];
  const float* cpos = (const float*)d_in[3];
  const float* Wq = (const float*)d_in[4];
  const float* Wk = (const float*)d_in[5];
  const float* Wv1 = (const float*)d_in[6];
  const float* Wv2 = (const float*)d_in[7];
  const float* Wo1 = (const float*)d_in[8];
  const float* Wo2 = (const float*)d_in[9];
  const float* ln1w = (const float*)d_in[10];
  const float* ln1b = (const float*)d_in[11];
  const float* ln2w = (const float*)d_in[12];
  const float* ln2b = (const float*)d_in[13];
  const float* f1W1 = (const float*)d_in[14];
  const float* f1W2 = (const float*)d_in[15];
  const float* f1b2 = (const float*)d_in[16];
  const float* f2W1 = (const float*)d_in[17];
  const float* f2W2 = (const float*)d_in[18];
  const float* f2b2 = (const float*)d_in[19];

  char* ws = (char*)d_ws;
  const size_t MB = 1024 * 1024;
  // workspace layout (~94 MB). af aliases q; acc partials alias xq (dead
  // after q GEMM); acm aliases v2 (dead after attf).
  bf16* q_ = (bf16*)(ws + 0);           // 32MB [32768,512]
  bf16* af_ = q_;                       // alias (see attf_kernel note)
  bf16* v1_ = (bf16*)(ws + 32 * MB);    // 32MB [32768,512]
  bf16* xq_ = (bf16*)(ws + 64 * MB);    // 16MB [32768,256]
  float* accp_ = (float*)(ws + 64 * MB);  // alias: 16MB fp32 [4,8,8,256,64]
  bf16* rf_ = xq_;                      // alias after acm (Wo1 GEMM output)
  bf16* k_ = (bf16*)(ws + 80 * MB);     // 2MB [2048,512]
  bf16* rc_ = (bf16*)(ws + 82 * MB);    // 1MB [2048,256]
  bf16* v2_ = (bf16*)(ws + 83 * MB);    // 2MB [2048,512]
  bf16* acm_ = v2_;                     // alias after attf
  float* colsum_ = (float*)(ws + 89 * MB);     // 256KB fp32 [4,8,8,256]
  bf16* wt_ = (bf16*)(ws + 89 * MB + 262144);  // 2MB transposed weights
  bf16* yf_ = q_;                       // alias: af dead after Wo1 GEMM
  bf16* tf_ = (bf16*)(ws + 16 * MB);    // upper half of q/af region
  bf16* yc_ = (bf16*)(ws + 92 * MB);    // 1MB
  bf16* tc_ = (bf16*)(ws + 93 * MB);    // 1MB

  bf16* WqT = wt_;
  bf16* WkT = WqT + 131072;
  bf16* Wv1T = WkT + 131072;
  bf16* Wv2T = Wv1T + 131072;
  bf16* Wo1T = Wv2T + 131072;
  bf16* Wo2T = Wo1T + 131072;
  bf16* f1W1T = Wo2T + 131072;
  bf16* f1W2T = f1W1T + 65536;
  bf16* f2W1T = f1W2T + 65536;
  bf16* f2W2T = f2W1T + 65536;

  float* out_feat = (float*)d_out;
  float* out_center = out_feat + (size_t)8 * 4096 * 256;

  WTArgs wa;
  const float* srcs[10] = {Wq, Wk, Wv1, Wv2, Wo1, Wo2, f1W1, f1W2, f2W1, f2W2};
  bf16* dsts[10] = {WqT, WkT, Wv1T, Wv2T, Wo1T, Wo2T, f1W1T, f1W2T, f2W1T, f2W2T};
  int Ks[10] = {256, 256, 256, 256, 512, 512, 256, 256, 256, 256};
  int Ns[10] = {512, 512, 512, 512, 256, 256, 256, 256, 256, 256};
  for (int i = 0; i < 10; ++i) {
    wa.src[i] = srcs[i];
    wa.dst[i] = dsts[i];
    wa.K[i] = Ks[i];
    wa.N[i] = Ns[i];
  }

  wtrans_kernel<<<dim3(8, 8, 10), 256, 0, stream>>>(wa);
  prep_xq_kernel<<<dim3(64, 4, 8), 256, 0, stream>>>(feat, pos, xq_);

  // q projection
  {
    GArg a{};
    a.A[0] = xq_; a.BT[0] = WqT; a.C[0] = q_; a.M[0] = 32768;
    gemm_kernel<0, bf16, bf16, bf16, false>
        <<<dim3(256, 4, 1), 256, 0, stream>>>(a, 512, 256);
  }
  // k projection with fused (center + cpos) add
  {
    GArg a{};
    a.A[0] = center; a.A2[0] = cpos; a.BT[0] = WkT; a.C[0] = k_;
    a.M[0] = 2048;
    gemm_kernel<0, bf16, bf16, float, true>
        <<<dim3(16, 4, 1), 256, 0, stream>>>(a, 512, 256);
  }
  // v1 + v2 projections (batched, fp32 A, async-split staging)
  {
    GArg a{};
    a.A[0] = feat; a.A[1] = center;
    a.BT[0] = Wv1T; a.BT[1] = Wv2T;
    a.C[0] = v1_; a.C[1] = v2_;
    a.M[0] = 32768; a.M[1] = 2048;
    gemm_kernel<0, bf16, bf16, float, false>
        <<<dim3(256, 4, 2), 256, 0, stream>>>(a, 512, 256);
  }

  // fused dual-softmax attention (atomic-free partials)
  attf_kernel<<<dim3(4, 8, 8), 256, 0, stream>>>(q_, k_, v1_, v2_, af_, accp_,
                                                 colsum_);
  acm_kernel<<<dim3(4096), 256, 0, stream>>>(accp_, colsum_, acm_);

  // Wo1 + Wo2 (batched, +resid)
  {
    GArg a{};
    a.A[0] = af_; a.A[1] = acm_;
    a.BT[0] = Wo1T; a.BT[1] = Wo2T;
    a.C[0] = rf_; a.C[1] = rc_;
    a.resid[0] = feat; a.resid[1] = center;
    a.M[0] = 32768; a.M[1] = 2048;
    gemm_kernel<2, bf16, float, bf16, false>
        <<<dim3(256, 2, 2), 256, 0, stream>>>(a, 256, 512);
  }
  // ln1 + ln2 (batched)
  ln_kernel<<<dim3(8704), 256, 0, stream>>>(rf_, rc_, ln1w, ln1b, ln2w, ln2b,
                                            yf_, yc_, 32768, 2048);
  // FFN W1 (relu) batched
  {
    GArg a{};
    a.A[0] = yf_; a.A[1] = yc_;
    a.BT[0] = f1W1T; a.BT[1] = f2W1T;
    a.C[0] = tf_; a.C[1] = tc_;
    a.M[0] = 32768; a.M[1] = 2048;
    gemm_kernel<1, bf16, bf16, bf16, false>
        <<<dim3(256, 2, 2), 256, 0, stream>>>(a, 256, 256);
  }
  // FFN W2 (+bias+resid, fp32 out) batched
  {
    GArg a{};
    a.A[0] = tf_; a.A[1] = tc_;
    a.BT[0] = f1W2T; a.BT[1] = f2W2T;
    a.C[0] = out_feat; a.C[1] = out_center;
    a.resid[0] = yf_; a.resid[1] = yc_;
    a.bias[0] = f1b2; a.bias[1] = f2b2;
    a.M[0] = 32768; a.M[1] = 2048;
    gemm_kernel<3, float, bf16, bf16, false>
        <<<dim3(256, 2, 2), 256, 0, stream>>>(a, 256, 256);
  }
}

// Round 9
// 351.915 us; speedup vs baseline: 1.0552x; 1.0080x over previous
//
#include <hip/hip_runtime.h>

typedef __bf16 bf16;
typedef __bf16 bf16x4 __attribute__((ext_vector_type(4)));
typedef __bf16 bf16x8 __attribute__((ext_vector_type(8)));
typedef float f32x4 __attribute__((ext_vector_type(4)));

#define MFMA16(a, b, c) __builtin_amdgcn_mfma_f32_16x16x32_bf16(a, b, c, 0, 0, 0)

// Problem constants: B=8, N=4096, M=256, DIM=256, HEADS=8, DIM_HEAD=64, INNER=512
// exp(S*scale) = exp2(S * 0.125 * log2(e))
#define CEXP 0.18033688011112042f

// ---------------------------------------------------------------------------
// Weight pre-transpose + downcast: W[K,N] fp32 -> WT[N,K] bf16 (10 matrices)
// ---------------------------------------------------------------------------
struct WTArgs {
  const float* src[10];
  bf16* dst[10];
  int K[10];
  int N[10];
};

__global__ __launch_bounds__(256) void wtrans_kernel(WTArgs args) {
  const int z = blockIdx.z;
  const int K = args.K[z], N = args.N[z];
  const int k0 = blockIdx.x * 64, n0 = blockIdx.y * 64;
  if (k0 >= K || n0 >= N) return;
  __shared__ float t[64][65];
  const int tx = threadIdx.x & 63, ty = threadIdx.x >> 6;
  const float* __restrict__ src = args.src[z];
  bf16* __restrict__ dst = args.dst[z];
#pragma unroll
  for (int i = 0; i < 16; ++i)
    t[ty + i * 4][tx] = src[(size_t)(k0 + ty + i * 4) * N + n0 + tx];
  __syncthreads();
#pragma unroll
  for (int i = 0; i < 16; ++i)
    dst[(size_t)(n0 + ty + i * 4) * K + k0 + tx] = (bf16)t[tx][ty + i * 4];
}

// ---------------------------------------------------------------------------
// xq[b][n][c] = feat[b][n][c] + pos[b][c][n]  (fp32 in, bf16 out)
// ---------------------------------------------------------------------------
__global__ __launch_bounds__(256) void prep_xq_kernel(
    const float* __restrict__ feat, const float* __restrict__ pos,
    bf16* __restrict__ xq) {
  const int n0 = blockIdx.x * 64;
  const int c0 = blockIdx.y * 64;
  const int b = blockIdx.z;
  __shared__ float t[64][65];
  const int tx = threadIdx.x & 63, ty = threadIdx.x >> 6;
#pragma unroll
  for (int i = 0; i < 16; ++i) {
    int c = ty + i * 4;
    t[c][tx] = pos[((size_t)b * 256 + c0 + c) * 4096 + n0 + tx];
  }
  __syncthreads();
#pragma unroll
  for (int i = 0; i < 16; ++i) {
    int n = ty + i * 4;
    size_t off = ((size_t)b * 4096 + n0 + n) * 256 + c0 + tx;
    xq[off] = (bf16)(feat[off] + t[tx][n]);
  }
}

// ---------------------------------------------------------------------------
// Staging helper: bf16 async DMA global->LDS (16B/lane, linear dest).
// ---------------------------------------------------------------------------
__device__ inline void stage16(const bf16* g, bf16* l) {
  __builtin_amdgcn_global_load_lds(
      (const __attribute__((address_space(1))) void*)g,
      (__attribute__((address_space(3))) void*)l, 16, 0, 0);
}

// Counted waitcnt (T4): tile-t drained, newer tiles stay in flight.
__device__ inline void wait_vm4() {
  asm volatile("s_waitcnt vmcnt(4) lgkmcnt(0)" ::: "memory");
}
__device__ inline void wait_vm2() {
  asm volatile("s_waitcnt vmcnt(2) lgkmcnt(0)" ::: "memory");
}
__device__ inline void wait_vm0() {
  asm volatile("s_waitcnt vmcnt(0) lgkmcnt(0)" ::: "memory");
}

// Epilogue helpers: vectorized resid load / C store.
__device__ inline f32x4 rload(const float* p) { return *(const f32x4*)p; }
__device__ inline f32x4 rload(const bf16* p) {
  bf16x4 t = *(const bf16x4*)p;
  return (f32x4){(float)t[0], (float)t[1], (float)t[2], (float)t[3]};
}
__device__ inline void cstore(float* p, f32x4 v) { *(f32x4*)p = v; }
__device__ inline void cstore(bf16* p, f32x4 v) {
  bf16x4 o;
  o[0] = (bf16)v[0]; o[1] = (bf16)v[1]; o[2] = (bf16)v[2]; o[3] = (bf16)v[3];
  *(bf16x4*)p = o;
}

// ---------------------------------------------------------------------------
// Generic GEMM, up to 3 problems batched via blockIdx.z. C = A @ B, B
// pre-transposed BT[N,K]. 128x128 tile, 4 waves, BK=32.
// COUNTED-VMCNT 3-BUFFER PIPELINE (T4): stage issued 2 tiles ahead; per step
//   s_waitcnt vmcnt(D) lgkmcnt(0)  (tile t drained; t+1,t+2 in flight)
//   raw s_barrier + sched_barrier(0)  (publish tile t; WAR for buf (t+2)%3,
//     which holds tile t-1 whose reads finished before this barrier)
//   restage t+2, then ds_read+MFMA on buf t%3.
// Never drains vmcnt to 0 in the loop (the __syncthreads drain-0 pattern
// exposed ~700cy HBM latency per step on these short-K GEMMs).
// fp32-A: A staged via reg+cvt (T14 split: loads issued BEFORE stageB so
// B-DMAs are newest; writeA after MFMA). SWAPPED-OPERAND MFMA -> vectorized
// epilogue. A2 != nullptr (fp32 only) fuses A+A2.
// EPI: 0=none, 1=relu, 2=+resid, 3=+bias+resid.
// ---------------------------------------------------------------------------
struct GArg {
  const void* A[3];
  const void* A2[3];
  const bf16* BT[3];
  void* C[3];
  const void* resid[3];
  const float* bias[3];
  int M[3];
};

template <int EPI, typename TO, typename TR, typename TA>
__global__ __launch_bounds__(256) void gemm_kernel(GArg g, int N, int K) {
  const int z = blockIdx.z;
  const int m0 = blockIdx.x * 128;
  if (m0 >= g.M[z]) return;
  constexpr bool F32A = sizeof(TA) == 4;
  const TA* A = (const TA*)g.A[z];
  const float* A2f = (const float*)g.A2[z];
  const bf16* BT = g.BT[z];
  TO* C = (TO*)g.C[z];
  const TR* resid = (const TR*)g.resid[z];
  const float* bias = g.bias[z];

  const int n0 = blockIdx.y * 128;
  const int tid = threadIdx.x;
  const int lane = tid & 63;
  const int w = tid >> 6;
  const int wr = (w >> 1) * 64, wc = (w & 1) * 64;
  const int l15 = lane & 15, quad = lane >> 4;

  __shared__ __align__(16) bf16 Al[3][128 * 32];  // 24KB (3-buf)
  __shared__ __align__(16) bf16 Bl[3][128 * 32];  // 24KB

  f32x4 acc[4][4];
#pragma unroll
  for (int i = 0; i < 4; ++i)
#pragma unroll
    for (int j = 0; j < 4; ++j) acc[i][j] = (f32x4){0.f, 0.f, 0.f, 0.f};

  const int sw = (((l15 >> 1) & 3) ^ quad) * 8;  // read-side swizzled granule

  f32x4 ar[2][2], ar2[2][2];  // fp32-A staging regs

  auto stageB = [&](int buf, int k0) {
#pragma unroll
    for (int c = 0; c < 2; ++c) {
      int idx = tid + c * 256;
      int row = idx >> 2;
      int gs = ((idx & 3) ^ ((row >> 1) & 3)) * 8;
      stage16(BT + (size_t)(n0 + row) * K + k0 + gs, Bl[buf] + idx * 8);
    }
  };
  auto stageA_dma = [&](int buf, int k0) {
    if constexpr (!F32A) {
#pragma unroll
      for (int c = 0; c < 2; ++c) {
        int idx = tid + c * 256;
        int row = idx >> 2;
        int gs = ((idx & 3) ^ ((row >> 1) & 3)) * 8;
        stage16((const bf16*)A + (size_t)(m0 + row) * K + k0 + gs,
                Al[buf] + idx * 8);
      }
    }
  };
  auto loadA = [&](int k0) {
    if constexpr (F32A) {
      const float* Af = (const float*)(const void*)A;
#pragma unroll
      for (int c = 0; c < 2; ++c) {
        int idx = tid + c * 256;
        int row = idx >> 2;
        int gs = ((idx & 3) ^ ((row >> 1) & 3)) * 8;
        const float* p = Af + (size_t)(m0 + row) * K + k0 + gs;
        ar[c][0] = *(const f32x4*)p;
        ar[c][1] = *((const f32x4*)p + 1);
        if (A2f) {
          const float* p2 = A2f + (size_t)(m0 + row) * K + k0 + gs;
          ar2[c][0] = *(const f32x4*)p2;
          ar2[c][1] = *((const f32x4*)p2 + 1);
        }
      }
    }
  };
  auto writeA = [&](int buf) {
    if constexpr (F32A) {
#pragma unroll
      for (int c = 0; c < 2; ++c) {
        int idx = tid + c * 256;
        f32x4 u = ar[c][0], v = ar[c][1];
        if (A2f) {
          u += ar2[c][0];
          v += ar2[c][1];
        }
        bf16x8 o;
#pragma unroll
        for (int e = 0; e < 4; ++e) {
          o[e] = (bf16)u[e];
          o[4 + e] = (bf16)v[e];
        }
        *(bf16x8*)(Al[buf] + idx * 8) = o;
      }
    }
  };

  // prologue: stage tiles 0 and 1 (per-tile issue order; B-DMAs last so the
  // fp32 writeA reg-waits don't drain them).
  if constexpr (F32A) {
    loadA(0);
    writeA(0);
    loadA(32);
    writeA(1);
    stageB(0, 0);
    stageB(1, 32);
  } else {
    stageA_dma(0, 0);
    stageB(0, 0);
    stageA_dma(1, 32);
    stageB(1, 32);
  }

  const int nt = K >> 5;
  for (int t = 0; t < nt; ++t) {
    // tile t drained; tiles t+1 (and t+2 after restage) stay in flight
    if (t + 1 < nt) {
      if constexpr (F32A)
        wait_vm2();
      else
        wait_vm4();
    } else {
      wait_vm0();
    }
    __builtin_amdgcn_s_barrier();        // publish tile t; WAR for (t+2)%3
    __builtin_amdgcn_sched_barrier(0);   // pin: no hoisting above the wait
    if (t + 2 < nt) {
      int nb = (t + 2) % 3;
      if constexpr (F32A) {
        loadA((t + 2) * 32);  // issue BEFORE stageB: B-DMAs stay newest
        stageB(nb, (t + 2) * 32);
      } else {
        stageA_dma(nb, (t + 2) * 32);
        stageB(nb, (t + 2) * 32);
      }
    }
    const int cb = t % 3;
    bf16x8 fa[4], fb[4];
#pragma unroll
    for (int i = 0; i < 4; ++i) {
      fa[i] = *(const bf16x8*)(Al[cb] + (wr + i * 16 + l15) * 32 + sw);
      fb[i] = *(const bf16x8*)(Bl[cb] + (wc + i * 16 + l15) * 32 + sw);
    }
#pragma unroll
    for (int i = 0; i < 4; ++i)
#pragma unroll
      for (int j = 0; j < 4; ++j)
        acc[i][j] = MFMA16(fb[j], fa[i], acc[i][j]);  // swapped: C^T frags
    if constexpr (F32A) {
      if (t + 2 < nt) writeA((t + 2) % 3);  // reg-wait lands post-MFMA
    }
  }

  // Epilogue: lane holds row=..+l15, 4 consecutive cols.
#pragma unroll
  for (int i = 0; i < 4; ++i) {
#pragma unroll
    for (int j = 0; j < 4; ++j) {
      int row = m0 + wr + i * 16 + l15;
      int col = n0 + wc + j * 16 + quad * 4;
      size_t off = (size_t)row * N + col;
      f32x4 v = acc[i][j];
      if constexpr (EPI == 1) {
#pragma unroll
        for (int e = 0; e < 4; ++e) v[e] = fmaxf(v[e], 0.f);
      }
      if constexpr (EPI == 2) v += rload(resid + off);
      if constexpr (EPI == 3)
        v += rload(resid + off) + *(const f32x4*)(bias + col);
      cstore(C + off, v);
    }
  }
}

// ---------------------------------------------------------------------------
// Fused dual-softmax attention (verified r6-r8, 79us): swapped QK^T with
// register-held P, ones-MFMA colsum, atomic-free partial slabs.
// ---------------------------------------------------------------------------
__global__ __launch_bounds__(256, 1) void attf_kernel(
    const bf16* q, const bf16* __restrict__ kk, const bf16* __restrict__ v1,
    const bf16* __restrict__ v2, bf16* af, float* __restrict__ acc_p,
    float* __restrict__ colsum_p) {
  const int nb = blockIdx.x;  // 4 blocks of 1024 rows
  const int h = blockIdx.y;
  const int b = blockIdx.z;
  const int tid = threadIdx.x;
  const int lane = tid & 63;
  const int w = tid >> 6;
  const int l15 = lane & 15, quad = lane >> 4;

  __shared__ __align__(16) bf16 klds[256 * 72];   // [m][d]        36.0 KB
  __shared__ __align__(16) bf16 v2T[64 * 264];    // [d][m-perm]   33.0 KB
  __shared__ __align__(16) bf16 v1T[2][64 * 72];  // [d][n_local]  18.0 KB
  __shared__ __align__(16) bf16 PT[256 * 72];     // [m][n_local]  36.0 KB

  // ---- prologue: stage K, v2T (perm'd cols), v1T[0]; q frags ch=0 ----
#pragma unroll
  for (int c = 0; c < 8; ++c) {
    int idx = tid + c * 256;  // 0..2047
    int m = idx >> 3;
    int dc = (idx & 7) * 8;
    *(bf16x8*)(klds + m * 72 + dc) =
        *(const bf16x8*)(kk + ((size_t)(b * 256 + m)) * 512 + h * 64 + dc);
  }
#pragma unroll
  for (int c = 0; c < 8; ++c) {
    int idx = tid + c * 256;
    int m = idx >> 3;
    int dc = (idx & 7) * 8;
    bf16x8 t =
        *(const bf16x8*)(v2 + ((size_t)(b * 256 + m)) * 512 + h * 64 + dc);
    // column position p = pi^-1(m) (verified round 3)
    int p = (m & ~31) |
            (((((m >> 2) & 3) << 3) + (m & 3)) + (((m >> 4) & 1) << 2));
#pragma unroll
    for (int j = 0; j < 8; ++j) v2T[(dc + j) * 264 + p] = t[j];
  }
  {
    const int nl = tid >> 3;
    const int dc = (tid & 7) * 8;
    const bf16* v1b =
        v1 + ((size_t)(b * 4096 + nb * 1024)) * 512 + h * 64 + dc;
    bf16x8 t0 = *(const bf16x8*)(v1b + (size_t)nl * 512);
    bf16x8 t1 = *(const bf16x8*)(v1b + (size_t)(nl + 32) * 512);
#pragma unroll
    for (int j = 0; j < 8; ++j) {
      v1T[0][(dc + j) * 72 + nl] = t0[j];
      v1T[0][(dc + j) * 72 + nl + 32] = t1[j];
    }
  }
  bf16x8 qa0, qa1;
  {
    int nrow = b * 4096 + nb * 1024 + w * 16 + l15;
    const bf16* qp = q + (size_t)nrow * 512 + h * 64 + quad * 8;
    qa0 = *(const bf16x8*)(qp);
    qa1 = *(const bf16x8*)(qp + 32);
  }

  f32x4 oc2[16];
#pragma unroll
  for (int i = 0; i < 16; ++i) oc2[i] = (f32x4){0.f, 0.f, 0.f, 0.f};
  f32x4 csa[4];
#pragma unroll
  for (int i = 0; i < 4; ++i) csa[i] = (f32x4){0.f, 0.f, 0.f, 0.f};
  bf16x8 ones8;
#pragma unroll
  for (int j = 0; j < 8; ++j) ones8[j] = (bf16)1.0f;

  __syncthreads();

  for (int ch = 0; ch < 16; ++ch) {
    // ---------------- phase A: QK^T (swapped) + O1 + af ----------------
    bf16x8 v1a, v1b;
    const int nl = tid >> 3;
    const int dc = (tid & 7) * 8;
    if (ch < 15) {
      const bf16* v1p =
          v1 + ((size_t)(b * 4096 + nb * 1024 + (ch + 1) * 64)) * 512 +
          h * 64 + dc;
      v1a = *(const bf16x8*)(v1p + (size_t)nl * 512);
      v1b = *(const bf16x8*)(v1p + (size_t)(nl + 32) * 512);
    }

    bf16x8 pa[8];
    float rs = 0.f;
#pragma unroll
    for (int mt = 0; mt < 16; ++mt) {
      const bf16* kp = klds + (mt * 16 + l15) * 72 + quad * 8;
      bf16x8 ka0 = *(const bf16x8*)(kp);
      bf16x8 ka1 = *(const bf16x8*)(kp + 32);
      f32x4 s = (f32x4){0.f, 0.f, 0.f, 0.f};
      s = MFMA16(ka0, qa0, s);  // swapped: A=K rows m, B=q cols n
      s = MFMA16(ka1, qa1, s);
      float e0 = exp2f(s[0] * CEXP);
      float e1 = exp2f(s[1] * CEXP);
      float e2 = exp2f(s[2] * CEXP);
      float e3 = exp2f(s[3] * CEXP);
      rs += (e0 + e1) + (e2 + e3);
      bf16 b0 = (bf16)e0, b1 = (bf16)e1, b2 = (bf16)e2, b3 = (bf16)e3;
      int mrow = mt * 16 + quad * 4;  // lane's E rows; col n = w*16+l15
      PT[(mrow + 0) * 72 + w * 16 + l15] = b0;
      PT[(mrow + 1) * 72 + w * 16 + l15] = b1;
      PT[(mrow + 2) * 72 + w * 16 + l15] = b2;
      PT[(mrow + 3) * 72 + w * 16 + l15] = b3;
      pa[mt >> 1][(mt & 1) * 4 + 0] = b0;
      pa[mt >> 1][(mt & 1) * 4 + 1] = b1;
      pa[mt >> 1][(mt & 1) * 4 + 2] = b2;
      pa[mt >> 1][(mt & 1) * 4 + 3] = b3;
    }

    // O1 = P @ v2 (A=v2T perm'd, B=pa from regs; lane->[n=l15][4 consec d])
    f32x4 o1[4];
#pragma unroll
    for (int i = 0; i < 4; ++i) o1[i] = (f32x4){0.f, 0.f, 0.f, 0.f};
#pragma unroll
    for (int ks = 0; ks < 8; ++ks) {
#pragma unroll
      for (int dt = 0; dt < 4; ++dt) {
        bf16x8 vb = *(const bf16x8*)(v2T + (dt * 16 + l15) * 264 + ks * 32 +
                                     quad * 8);
        o1[dt] = MFMA16(vb, pa[ks], o1[dt]);
      }
    }
    {
      float rsf = rs + __shfl_xor(rs, 16, 64);
      rsf += __shfl_xor(rsf, 32, 64);
      float inv = 1.f / rsf;
      int n = nb * 1024 + ch * 64 + w * 16 + l15;
      bf16* ap = af + ((size_t)(b * 4096 + n)) * 512 + h * 64 + quad * 4;
#pragma unroll
      for (int dt = 0; dt < 4; ++dt) {
        bf16x4 ov;
        ov[0] = (bf16)(o1[dt][0] * inv);
        ov[1] = (bf16)(o1[dt][1] * inv);
        ov[2] = (bf16)(o1[dt][2] * inv);
        ov[3] = (bf16)(o1[dt][3] * inv);
        *(bf16x4*)(ap + dt * 16) = ov;
      }
    }

    if (ch < 15) {
      bf16* dst = v1T[(ch + 1) & 1];
#pragma unroll
      for (int j = 0; j < 8; ++j) {
        dst[(dc + j) * 72 + nl] = v1a[j];
        dst[(dc + j) * 72 + nl + 32] = v1b[j];
      }
    }
    __syncthreads();  // PT (+next v1T) ready

    // ---------------- phase B: O2 + colsum-MFMA ----------------
    bf16x8 qn0 = qa0, qn1 = qa1;
    if (ch < 15) {
      int nrow = b * 4096 + nb * 1024 + (ch + 1) * 64 + w * 16 + l15;
      const bf16* qp = q + (size_t)nrow * 512 + h * 64 + quad * 8;
      qn0 = *(const bf16x8*)(qp);
      qn1 = *(const bf16x8*)(qp + 32);
    }

    const bf16* vc = v1T[ch & 1];
#pragma unroll
    for (int ks = 0; ks < 2; ++ks) {
      bf16x8 vbv[4];
#pragma unroll
      for (int dt = 0; dt < 4; ++dt)
        vbv[dt] = *(const bf16x8*)(vc + (dt * 16 + l15) * 72 + ks * 32 +
                                   quad * 8);
#pragma unroll
      for (int mq = 0; mq < 4; ++mq) {
        bf16x8 pa2 = *(const bf16x8*)(PT + (mq * 64 + w * 16 + l15) * 72 +
                                      ks * 32 + quad * 8);
#pragma unroll
        for (int dt = 0; dt < 4; ++dt)
          oc2[mq * 4 + dt] = MFMA16(vbv[dt], pa2, oc2[mq * 4 + dt]);
        csa[mq] = MFMA16(pa2, ones8, csa[mq]);  // colsum over n (ones-MFMA)
      }
    }
    __syncthreads();  // WAR: PT/v1T reads done before next ch restage
    qa0 = qn0;
    qa1 = qn1;
  }

  // ---- epilogue: per-block partial slabs indexed by nb ----
  const size_t slab = (size_t)(nb * 64 + b * 8 + h);
  if (l15 == 0) {
#pragma unroll
    for (int mq = 0; mq < 4; ++mq)
#pragma unroll
      for (int r = 0; r < 4; ++r)
        colsum_p[slab * 256 + mq * 64 + w * 16 + quad * 4 + r] = csa[mq][r];
  }
  float* base = acc_p + slab * (256 * 64);
#pragma unroll
  for (int mq = 0; mq < 4; ++mq) {
    int m = mq * 64 + w * 16 + l15;
#pragma unroll
    for (int dt = 0; dt < 4; ++dt)
      *(f32x4*)(base + m * 64 + dt * 16 + quad * 4) = oc2[mq * 4 + dt];
  }
}

// ---------------------------------------------------------------------------
// acm[b][m][h*64+d] = sum_p acc_p[p][b][h][m][d] / sum_p colsum_p[p][b][h][m]
// ---------------------------------------------------------------------------
__global__ __launch_bounds__(256) void acm_kernel(
    const float* __restrict__ acc_p, const float* __restrict__ colsum_p,
    bf16* __restrict__ acm) {
  int idx = blockIdx.x * 256 + threadIdx.x;  // 8*256*512 total
  int d = idx & 63;
  int h = (idx >> 6) & 7;
  int m = (idx >> 9) & 255;
  int b = idx >> 17;
  float cv = 0.f, v = 0.f;
#pragma unroll
  for (int p = 0; p < 4; ++p) {
    cv += colsum_p[((size_t)(p * 64 + b * 8 + h)) * 256 + m];
    v += acc_p[(((size_t)(p * 64 + b * 8 + h)) * 256 + m) * 64 + d];
  }
  acm[idx] = (bf16)(v / cv);
}

// ---------------------------------------------------------------------------
// LayerNorm over last dim (256), dual-problem batched by row range.
// ---------------------------------------------------------------------------
__global__ __launch_bounds__(256) void ln_kernel(
    const bf16* __restrict__ x0, const bf16* __restrict__ x1,
    const float* __restrict__ w0, const float* __restrict__ b0,
    const float* __restrict__ w1, const float* __restrict__ b1,
    bf16* __restrict__ y0, bf16* __restrict__ y1, int rows0, int rows1) {
  int wave = threadIdx.x >> 6;
  int lane = threadIdx.x & 63;
  int row = blockIdx.x * 4 + wave;
  const bf16* x;
  const float *wv, *bv;
  bf16* y;
  if (row < rows0) {
    x = x0; wv = w0; bv = b0; y = y0;
  } else {
    row -= rows0;
    if (row >= rows1) return;
    x = x1; wv = w1; bv = b1; y = y1;
  }
  const bf16* xr = x + (size_t)row * 256;
  bf16x4 v = *(const bf16x4*)(xr + lane * 4);
  float f0 = v[0], f1 = v[1], f2 = v[2], f3 = v[3];
  float s = f0 + f1 + f2 + f3;
  float ss = f0 * f0 + f1 * f1 + f2 * f2 + f3 * f3;
#pragma unroll
  for (int m = 1; m < 64; m <<= 1) {
    s += __shfl_xor(s, m, 64);
    ss += __shfl_xor(ss, m, 64);
  }
  float mean = s * (1.f / 256.f);
  float var = ss * (1.f / 256.f) - mean * mean;
  float rstd = rsqrtf(var + 1e-5f);
  f32x4 wq = *(const f32x4*)(wv + lane * 4);
  f32x4 bq = *(const f32x4*)(bv + lane * 4);
  bf16x4 o;
  o[0] = (bf16)((f0 - mean) * rstd * wq[0] + bq[0]);
  o[1] = (bf16)((f1 - mean) * rstd * wq[1] + bq[1]);
  o[2] = (bf16)((f2 - mean) * rstd * wq[2] + bq[2]);
  o[3] = (bf16)((f3 - mean) * rstd * wq[3] + bq[3]);
  *(bf16x4*)(y + (size_t)row * 256 + lane * 4) = o;
}

// ---------------------------------------------------------------------------
extern "C" void kernel_launch(void* const* d_in, const int* in_sizes, int n_in,
                              void* d_out, int out_size, void* d_ws,
                              size_t ws_size, hipStream_t stream) {
  const float* feat = (const float*)d_in[0];
  const float* center = (const float*)d_in[1];
  const float* pos = (const float*)d_in[2];
  const float* cpos = (const float*)d_in[3];
  const float* Wq = (const float*)d_in[4];
  const float* Wk = (const float*)d_in[5];
  const float* Wv1 = (const float*)d_in[6];
  const float* Wv2 = (const float*)d_in[7];
  const float* Wo1 = (const float*)d_in[8];
  const float* Wo2 = (const float*)d_in[9];
  const float* ln1w = (const float*)d_in[10];
  const float* ln1b = (const float*)d_in[11];
  const float* ln2w = (const float*)d_in[12];
  const float* ln2b = (const float*)d_in[13];
  const float* f1W1 = (const float*)d_in[14];
  const float* f1W2 = (const float*)d_in[15];
  const float* f1b2 = (const float*)d_in[16];
  const float* f2W1 = (const float*)d_in[17];
  const float* f2W2 = (const float*)d_in[18];
  const float* f2b2 = (const float*)d_in[19];

  char* ws = (char*)d_ws;
  const size_t MB = 1024 * 1024;
  // workspace layout (~94 MB). af aliases q; acc partials alias xq (dead
  // after q GEMM); acm aliases v2 (dead after attf).
  bf16* q_ = (bf16*)(ws + 0);           // 32MB [32768,512]
  bf16* af_ = q_;                       // alias (see attf_kernel note)
  bf16* v1_ = (bf16*)(ws + 32 * MB);    // 32MB [32768,512]
  bf16* xq_ = (bf16*)(ws + 64 * MB);    // 16MB [32768,256]
  float* accp_ = (float*)(ws + 64 * MB);  // alias: 16MB fp32 [4,8,8,256,64]
  bf16* rf_ = xq_;                      // alias after acm (Wo1 GEMM output)
  bf16* k_ = (bf16*)(ws + 80 * MB);     // 2MB [2048,512]
  bf16* rc_ = (bf16*)(ws + 82 * MB);    // 1MB [2048,256]
  bf16* v2_ = (bf16*)(ws + 83 * MB);    // 2MB [2048,512]
  bf16* acm_ = v2_;                     // alias after attf
  float* colsum_ = (float*)(ws + 89 * MB);     // 256KB fp32 [4,8,8,256]
  bf16* wt_ = (bf16*)(ws + 89 * MB + 262144);  // 2MB transposed weights
  bf16* yf_ = q_;                       // alias: af dead after Wo1 GEMM
  bf16* tf_ = (bf16*)(ws + 16 * MB);    // upper half of q/af region
  bf16* yc_ = (bf16*)(ws + 92 * MB);    // 1MB
  bf16* tc_ = (bf16*)(ws + 93 * MB);    // 1MB

  bf16* WqT = wt_;
  bf16* WkT = WqT + 131072;
  bf16* Wv1T = WkT + 131072;
  bf16* Wv2T = Wv1T + 131072;
  bf16* Wo1T = Wv2T + 131072;
  bf16* Wo2T = Wo1T + 131072;
  bf16* f1W1T = Wo2T + 131072;
  bf16* f1W2T = f1W1T + 65536;
  bf16* f2W1T = f1W2T + 65536;
  bf16* f2W2T = f2W1T + 65536;

  float* out_feat = (float*)d_out;
  float* out_center = out_feat + (size_t)8 * 4096 * 256;

  WTArgs wa;
  const float* srcs[10] = {Wq, Wk, Wv1, Wv2, Wo1, Wo2, f1W1, f1W2, f2W1, f2W2};
  bf16* dsts[10] = {WqT, WkT, Wv1T, Wv2T, Wo1T, Wo2T, f1W1T, f1W2T, f2W1T, f2W2T};
  int Ks[10] = {256, 256, 256, 256, 512, 512, 256, 256, 256, 256};
  int Ns[10] = {512, 512, 512, 512, 256, 256, 256, 256, 256, 256};
  for (int i = 0; i < 10; ++i) {
    wa.src[i] = srcs[i];
    wa.dst[i] = dsts[i];
    wa.K[i] = Ks[i];
    wa.N[i] = Ns[i];
  }

  wtrans_kernel<<<dim3(8, 8, 10), 256, 0, stream>>>(wa);
  prep_xq_kernel<<<dim3(64, 4, 8), 256, 0, stream>>>(feat, pos, xq_);

  // q projection (bf16 A)
  {
    GArg a{};
    a.A[0] = xq_; a.BT[0] = WqT; a.C[0] = q_; a.M[0] = 32768;
    gemm_kernel<0, bf16, bf16, bf16>
        <<<dim3(256, 4, 1), 256, 0, stream>>>(a, 512, 256);
  }
  // v1 + v2 + k projections (fp32 A; k fuses center+cpos via A2)
  {
    GArg a{};
    a.A[0] = feat; a.A[1] = center; a.A[2] = center;
    a.A2[2] = cpos;
    a.BT[0] = Wv1T; a.BT[1] = Wv2T; a.BT[2] = WkT;
    a.C[0] = v1_; a.C[1] = v2_; a.C[2] = k_;
    a.M[0] = 32768; a.M[1] = 2048; a.M[2] = 2048;
    gemm_kernel<0, bf16, bf16, float>
        <<<dim3(256, 4, 3), 256, 0, stream>>>(a, 512, 256);
  }

  // fused dual-softmax attention (atomic-free partials)
  attf_kernel<<<dim3(4, 8, 8), 256, 0, stream>>>(q_, k_, v1_, v2_, af_, accp_,
                                                 colsum_);
  acm_kernel<<<dim3(4096), 256, 0, stream>>>(accp_, colsum_, acm_);

  // Wo1 + Wo2 (batched, +resid)
  {
    GArg a{};
    a.A[0] = af_; a.A[1] = acm_;
    a.BT[0] = Wo1T; a.BT[1] = Wo2T;
    a.C[0] = rf_; a.C[1] = rc_;
    a.resid[0] = feat; a.resid[1] = center;
    a.M[0] = 32768; a.M[1] = 2048;
    gemm_kernel<2, bf16, float, bf16>
        <<<dim3(256, 2, 2), 256, 0, stream>>>(a, 256, 512);
  }
  // ln1 + ln2 (batched)
  ln_kernel<<<dim3(8704), 256, 0, stream>>>(rf_, rc_, ln1w, ln1b, ln2w, ln2b,
                                            yf_, yc_, 32768, 2048);
  // FFN W1 (relu) batched
  {
    GArg a{};
    a.A[0] = yf_; a.A[1] = yc_;
    a.BT[0] = f1W1T; a.BT[1] = f2W1T;
    a.C[0] = tf_; a.C[1] = tc_;
    a.M[0] = 32768; a.M[1] = 2048;
    gemm_kernel<1, bf16, bf16, bf16>
        <<<dim3(256, 2, 2), 256, 0, stream>>>(a, 256, 256);
  }
  // FFN W2 (+bias+resid, fp32 out) batched
  {
    GArg a{};
    a.A[0] = tf_; a.A[1] = tc_;
    a.BT[0] = f1W2T; a.BT[1] = f2W2T;
    a.C[0] = out_feat; a.C[1] = out_center;
    a.resid[0] = yf_; a.resid[1] = yc_;
    a.bias[0] = f1b2; a.bias[1] = f2b2;
    a.M[0] = 32768; a.M[1] = 2048;
    gemm_kernel<3, float, bf16, bf16>
        <<<dim3(256, 2, 2), 256, 0, stream>>>(a, 256, 256);
  }
}